// Round 12
// baseline (279.159 us; speedup 1.0000x reference)
//
#include <hip/hip_runtime.h>
#include <hip/hip_bf16.h>

#define N_NODES 8192
#define N_EDGES 262144
#define IN_DIM 256
#define HID 256
#define OUT_DIM 64
#define PATH_DIM 64
#define NHEADS 4
#define DH 16
#define KSPLIT 8
#define SPLIT_KEYS (N_NODES / KSPLIT)   // 1024
#define NITER (SPLIT_KEYS / 64)         // 16

typedef __attribute__((ext_vector_type(8))) short bf16x8;
typedef __attribute__((ext_vector_type(4))) short bf16x4;
typedef __attribute__((ext_vector_type(4))) float f32x4;

__device__ __forceinline__ ushort f2bf(float f) {
  union { float f; unsigned int u; } c;
  c.f = f;
  unsigned int u = c.u;
  u += 0x7fffu + ((u >> 16) & 1u);
  return (ushort)(u >> 16);
}

__device__ __forceinline__ float bf2f(ushort u) {
  union { float f; unsigned int u; } c;
  c.u = ((unsigned int)u) << 16;
  return c.f;
}

__device__ __forceinline__ float fast_exp2(float x) {
  float r;
  asm("v_exp_f32 %0, %1" : "=v"(r) : "v"(x));
  return r;
}

__device__ __forceinline__ unsigned pack_bf16(float a, float b) {
  union { __hip_bfloat162 h; unsigned u; } c;
  c.h = __float22bfloat162_rn(make_float2(a, b));
  return c.u;
}

// PV matrix op: 16x16x16 bf16 (K=16).
#if __has_builtin(__builtin_amdgcn_mfma_f32_16x16x16bf16_1k)
__device__ __forceinline__ f32x4 mfma16(bf16x4 a, bf16x4 b, f32x4 c) {
  return __builtin_amdgcn_mfma_f32_16x16x16bf16_1k(a, b, c, 0, 0, 0);
}
#else
__device__ __forceinline__ f32x4 mfma16(bf16x4 a, bf16x4 b, f32x4 c) {
  f32x4 d;
  asm volatile("v_mfma_f32_16x16x16_bf16 %0, %1, %2, %3\n\ts_nop 7\n\ts_nop 3"
               : "=v"(d) : "v"(a), "v"(b), "v"(c));
  return d;
}
#endif

// ---------------- graph setup ----------------

__global__ __launch_bounds__(256) void init_graph(int* deg, int* cursor) {
  int i = blockIdx.x * 256 + threadIdx.x;
  if (i < N_NODES) { deg[i] = 1; cursor[i] = 0; }   // deg starts at 1 (self loop)
}

__global__ __launch_bounds__(256) void count_deg(const int* __restrict__ dst,
                                                 int* __restrict__ deg) {
  int e = blockIdx.x * 256 + threadIdx.x;
  if (e < N_EDGES) atomicAdd(&deg[dst[e]], 1);
}

__global__ __launch_bounds__(256) void scan_rows(const int* __restrict__ deg,
                                                 int* __restrict__ row_off,
                                                 float* __restrict__ dinv) {
  __shared__ int part[256];
  int t = threadIdx.x;
  int base = t * 32;
  int local[32];
  int s = 0;
  #pragma unroll
  for (int i = 0; i < 32; ++i) {
    int c = deg[base + i] - 1;
    local[i] = s;
    s += c;
  }
  part[t] = s;
  __syncthreads();
  for (int d = 1; d < 256; d <<= 1) {
    int v = (t >= d) ? part[t - d] : 0;
    __syncthreads();
    part[t] += v;
    __syncthreads();
  }
  int prev = (t == 0) ? 0 : part[t - 1];
  #pragma unroll
  for (int i = 0; i < 32; ++i) {
    row_off[base + i] = prev + local[i];
    dinv[base + i] = rsqrtf((float)deg[base + i]);
  }
}

__global__ __launch_bounds__(256) void fill_csr(const int* __restrict__ src,
                                                const int* __restrict__ dst,
                                                const int* __restrict__ row_off,
                                                int* __restrict__ cursor,
                                                int* __restrict__ csr) {
  int e = blockIdx.x * 256 + threadIdx.x;
  if (e < N_EDGES) {
    int d = dst[e];
    int p = atomicAdd(&cursor[d], 1);
    csr[row_off[d] + p] = src[e];
  }
}

// ---------------- fused prep: fused qkv-weight, splits, transposes, x->bf16 ----------------
// block ranges:
//  [0,2048)     convert x -> Axpa[:,0:256] bf16
//  [2048,2240)  W'' = pe_w @ in_proj_w^T  (cols<64 scaled by SC)  [256][192]
//  [2240]       b'' = pe_b @ in_proj_w^T + in_proj_b (cols<64 * SC)
//  [2241,2257)  Wt_out transpose [64][64]
//  [2257,2577)  w1 bf16 hi/lo split -> [256][320]
//  [2577,2833)  w2 split -> [256][256]
//  [2833,2897)  w3 split -> [64][256]

__global__ __launch_bounds__(256) void prep(const float* __restrict__ x,
                                            const float* __restrict__ pe_w,
                                            const float* __restrict__ pe_b,
                                            const float* __restrict__ in_proj_w,
                                            const float* __restrict__ in_proj_b,
                                            const float* __restrict__ out_proj_w,
                                            const float* __restrict__ w1,
                                            const float* __restrict__ w2,
                                            const float* __restrict__ w3,
                                            ushort* __restrict__ Axpa,
                                            float* __restrict__ Wpp,
                                            float* __restrict__ bpp,
                                            float* __restrict__ WtO,
                                            ushort* __restrict__ Bt1hi, ushort* __restrict__ Bt1lo,
                                            ushort* __restrict__ Bt2hi, ushort* __restrict__ Bt2lo,
                                            ushort* __restrict__ Bt3hi, ushort* __restrict__ Bt3lo) {
  const float SC = 0.36067376022224085f;  // 0.25 * log2(e)
  const int b = blockIdx.x;
  const int t = threadIdx.x;
  if (b < 2048) {
    int e = b * 256 + t;
    int n = e >> 6, qi = (e & 63) << 2;
    float4 v = *reinterpret_cast<const float4*>(x + (size_t)n * 256 + qi);
    *reinterpret_cast<ushort4*>(Axpa + (size_t)n * 320 + qi) =
        make_ushort4(f2bf(v.x), f2bf(v.y), f2bf(v.z), f2bf(v.w));
  } else if (b < 2240) {
    int e = (b - 2048) * 256 + t;
    int k = e / 192, c = e % 192;
    float s = 0.f;
    for (int j = 0; j < 64; ++j) s += pe_w[k * 64 + j] * in_proj_w[c * 64 + j];
    if (c < 64) s *= SC;
    Wpp[k * 192 + c] = s;
  } else if (b == 2240) {
    if (t < 192) {
      float s = 0.f;
      for (int j = 0; j < 64; ++j) s += pe_b[j] * in_proj_w[t * 64 + j];
      s += in_proj_b[t];
      if (t < 64) s *= SC;
      bpp[t] = s;
    }
  } else if (b < 2257) {
    int e = (b - 2241) * 256 + t;
    int r = e >> 6, c = e & 63;
    WtO[c * 64 + r] = out_proj_w[e];
  } else if (b < 2577) {
    int e = (b - 2257) * 256 + t;
    int k = e >> 8, n = e & 255;
    float v = w1[e];
    ushort hi = f2bf(v);
    Bt1hi[(size_t)n * 320 + k] = hi;
    Bt1lo[(size_t)n * 320 + k] = f2bf(v - bf2f(hi));
  } else if (b < 2833) {
    int e = (b - 2577) * 256 + t;
    int k = e >> 8, n = e & 255;
    float v = w2[e];
    ushort hi = f2bf(v);
    Bt2hi[(size_t)n * 256 + k] = hi;
    Bt2lo[(size_t)n * 256 + k] = f2bf(v - bf2f(hi));
  } else {
    int e = (b - 2833) * 256 + t;
    int k = e >> 6, n = e & 63;
    float v = w3[e];
    ushort hi = f2bf(v);
    Bt3hi[(size_t)n * 256 + k] = hi;
    Bt3lo[(size_t)n * 256 + k] = f2bf(v - bf2f(hi));
  }
}

// ---------------- qkv GEMM: x[8192x256] @ W''[256x192] + b'' -> Qbf/Kbf/Vtb bf16 ----------------
// grid (3,128): blockIdx.x = 0 (q), 1 (k), 2 (v). SC pre-folded into W''/b'' q-cols.

__global__ __launch_bounds__(256) void gemm_qkv(const float* __restrict__ x,
                                                const float* __restrict__ Wpp,
                                                const float* __restrict__ bpp,
                                                ushort* __restrict__ Qbf,
                                                ushort* __restrict__ Kbf,
                                                ushort* __restrict__ Vtb) {
  __shared__ __align__(16) float As[16][64];
  __shared__ __align__(16) float Bs[16][68];
  const int bm = blockIdx.y * 64;
  const int bx = blockIdx.x;
  const int bn = bx * 64;
  const int t = threadIdx.x;
  const int tx = t & 15, ty = t >> 4;
  const int am = t >> 2, ak = (t & 3) << 2;
  const int bk = t >> 4, bn4 = (t & 15) << 2;
  float acc[4][4] = {};
  for (int k0 = 0; k0 < 256; k0 += 16) {
    float4 av = *reinterpret_cast<const float4*>(x + (size_t)(bm + am) * 256 + k0 + ak);
    As[ak + 0][am] = av.x; As[ak + 1][am] = av.y;
    As[ak + 2][am] = av.z; As[ak + 3][am] = av.w;
    float4 bv = *reinterpret_cast<const float4*>(Wpp + (size_t)(k0 + bk) * 192 + bn + bn4);
    *reinterpret_cast<float4*>(&Bs[bk][bn4]) = bv;
    __syncthreads();
    #pragma unroll
    for (int k = 0; k < 16; ++k) {
      float4 a = *reinterpret_cast<const float4*>(&As[k][ty << 2]);
      float4 b = *reinterpret_cast<const float4*>(&Bs[k][tx << 2]);
      acc[0][0] += a.x * b.x; acc[0][1] += a.x * b.y; acc[0][2] += a.x * b.z; acc[0][3] += a.x * b.w;
      acc[1][0] += a.y * b.x; acc[1][1] += a.y * b.y; acc[1][2] += a.y * b.z; acc[1][3] += a.y * b.w;
      acc[2][0] += a.z * b.x; acc[2][1] += a.z * b.y; acc[2][2] += a.z * b.z; acc[2][3] += a.z * b.w;
      acc[3][0] += a.w * b.x; acc[3][1] += a.w * b.y; acc[3][2] += a.w * b.z; acc[3][3] += a.w * b.w;
    }
    __syncthreads();
  }
  const int cl = tx << 2;
  const int h = cl >> 4, d = cl & 15;
  float4 bb = *reinterpret_cast<const float4*>(bpp + bn + cl);
  const ushort4 zz = make_ushort4(0, 0, 0, 0);
  #pragma unroll
  for (int i = 0; i < 4; ++i) {
    int row = bm + (ty << 2) + i;
    float o0 = acc[i][0] + bb.x, o1 = acc[i][1] + bb.y;
    float o2 = acc[i][2] + bb.z, o3 = acc[i][3] + bb.w;
    ushort4 u = make_ushort4(f2bf(o0), f2bf(o1), f2bf(o2), f2bf(o3));
    if (bx == 0) {
      *reinterpret_cast<ushort4*>(Qbf + ((size_t)h * 8192 + row) * 32 + d) = u;
      *reinterpret_cast<ushort4*>(Qbf + ((size_t)h * 8192 + row) * 32 + d + 16) = zz;
    } else if (bx == 1) {
      *reinterpret_cast<ushort4*>(Kbf + ((size_t)h * 8192 + row) * 32 + d) = u;
      *reinterpret_cast<ushort4*>(Kbf + ((size_t)h * 8192 + row) * 32 + d + 16) = zz;
    } else {
      Vtb[((size_t)h * 16 + d + 0) * 8192 + row] = u.x;
      Vtb[((size_t)h * 16 + d + 1) * 8192 + row] = u.y;
      Vtb[((size_t)h * 16 + d + 2) * 8192 + row] = u.z;
      Vtb[((size_t)h * 16 + d + 3) * 8192 + row] = u.w;
    }
  }
}

// ---------------- MFMA flash attention v5.1 (round-10 proven form) ----------------
// grid (128,4,KSPLIT) x 256. In-register P; fp32 VALU denominator + shuffle reduce.

__global__ __launch_bounds__(256) void attn_mfma5(const ushort* __restrict__ Qbf,
                                                  const ushort* __restrict__ Kbf,
                                                  const ushort* __restrict__ Vtb,
                                                  float* __restrict__ Opart,
                                                  float* __restrict__ Wpart) {
  const int h  = blockIdx.y;
  const int qb = blockIdx.x;
  const int kz = blockIdx.z;
  const int t  = threadIdx.x;
  const int wv = t >> 6;
  const int l  = t & 63;
  const int lg = l >> 4;
  const int lc = l & 15;

  __shared__ float red_o[3][64][17];
  __shared__ float red_w[3][64];

  bf16x8 qf[4];
  {
    const ushort* qbase = Qbf + ((size_t)h * 8192 + qb * 64) * 32;
    #pragma unroll
    for (int qt = 0; qt < 4; ++qt)
      qf[qt] = *reinterpret_cast<const bf16x8*>(qbase + (qt * 16 + lc) * 32 + lg * 8);
  }

  const ushort* kptr =
      Kbf + ((size_t)h * 8192 + kz * SPLIT_KEYS + wv * 16 + lc) * 32 + lg * 8;
  const ushort* vptr =
      Vtb + ((size_t)h * 16 + lc) * 8192 + kz * SPLIT_KEYS + wv * 16 + lg * 4;

  f32x4 oacc[4] = {{0.f, 0.f, 0.f, 0.f}, {0.f, 0.f, 0.f, 0.f},
                   {0.f, 0.f, 0.f, 0.f}, {0.f, 0.f, 0.f, 0.f}};
  float wsum[4] = {0.f, 0.f, 0.f, 0.f};

  bf16x8 kf = *reinterpret_cast<const bf16x8*>(kptr);
  bf16x4 vf = *reinterpret_cast<const bf16x4*>(vptr);

  for (int c = 0; c < NITER; ++c) {
    bf16x8 kf_n;
    bf16x4 vf_n;
    if (c + 1 < NITER) {
      kf_n = *reinterpret_cast<const bf16x8*>(kptr + (size_t)(c + 1) * 64 * 32);
      vf_n = *reinterpret_cast<const bf16x4*>(vptr + (size_t)(c + 1) * 64);
    }

    f32x4 s[4];
    #pragma unroll
    for (int qt = 0; qt < 4; ++qt) {
      f32x4 z = {0.f, 0.f, 0.f, 0.f};
      s[qt] = __builtin_amdgcn_mfma_f32_16x16x32_bf16(kf, qf[qt], z, 0, 0, 0);
    }

    #pragma unroll
    for (int qt = 0; qt < 4; ++qt) {
      float e0 = fast_exp2(s[qt][0]);
      float e1 = fast_exp2(s[qt][1]);
      float e2 = fast_exp2(s[qt][2]);
      float e3 = fast_exp2(s[qt][3]);
      wsum[qt] += (e0 + e1) + (e2 + e3);
      union { uint2 u; bf16x4 v; } pu;
      pu.u.x = pack_bf16(e0, e1);
      pu.u.y = pack_bf16(e2, e3);
      oacc[qt] = mfma16(pu.v, vf, oacc[qt]);
    }

    kf = kf_n;
    vf = vf_n;
  }

  #pragma unroll
  for (int qt = 0; qt < 4; ++qt) {
    float v = wsum[qt];
    v += __shfl_xor(v, 16);
    v += __shfl_xor(v, 32);
    wsum[qt] = v;   // strip total for q = qt*16 + lc
  }

  if (wv > 0) {
    #pragma unroll
    for (int qt = 0; qt < 4; ++qt) {
      #pragma unroll
      for (int r = 0; r < 4; ++r)
        red_o[wv - 1][qt * 16 + lg * 4 + r][lc] = oacc[qt][r];
      if (lg == 0) red_w[wv - 1][qt * 16 + lc] = wsum[qt];
    }
  }
  __syncthreads();

  if (wv == 0) {
    const size_t obase = ((size_t)(kz * NHEADS + h) * N_NODES + qb * 64);
    #pragma unroll
    for (int qt = 0; qt < 4; ++qt) {
      #pragma unroll
      for (int r = 0; r < 4; ++r) {
        const int q = qt * 16 + lg * 4 + r;
        float o = oacc[qt][r] + red_o[0][q][lc] + red_o[1][q][lc] + red_o[2][q][lc];
        Opart[(obase + q) * 16 + lc] = o;
      }
      if (lg == 0) {
        const int q = qt * 16 + lc;
        Wpart[obase + q] = wsum[qt] + red_w[0][q] + red_w[1][q] + red_w[2][q];
      }
    }
  }
}

// ---------------- pa GEMM with fused split-combine staging ----------------
// A[n][k=h*16+d] = (sum_s Opart[s][h][n][d]) / (sum_s Wpart[s][h][n]);
// pa = A @ Wt_out + out_proj_b  -> bf16 into Axpa[:,256:320]. grid (1,128).

__global__ __launch_bounds__(256) void gemm_pa(const float* __restrict__ Opart,
                                               const float* __restrict__ Wpart,
                                               const float* __restrict__ WtO,
                                               const float* __restrict__ ob,
                                               ushort* __restrict__ Axpa) {
  __shared__ __align__(16) float As[16][64];
  __shared__ __align__(16) float Bs[16][68];
  const int bm = blockIdx.y * 64;
  const int t = threadIdx.x;
  const int tx = t & 15, ty = t >> 4;
  const int am = t >> 2, ak = (t & 3) << 2;
  const int bk = t >> 4, bn4 = (t & 15) << 2;
  float acc[4][4] = {};
  for (int k0 = 0; k0 < 64; k0 += 16) {
    const int kk = k0 + ak;
    const int row = bm + am;
    const int h = kk >> 4, d = kk & 15;
    float ax = 0.f, ay = 0.f, az = 0.f, aw = 0.f, ws = 0.f;
    #pragma unroll
    for (int s = 0; s < KSPLIT; ++s) {
      const size_t rb = (size_t)(s * NHEADS + h) * N_NODES + row;
      float4 v = *reinterpret_cast<const float4*>(Opart + rb * 16 + d);
      ax += v.x; ay += v.y; az += v.z; aw += v.w;
      ws += Wpart[rb];
    }
    float inv = 1.f / ws;
    As[ak + 0][am] = ax * inv; As[ak + 1][am] = ay * inv;
    As[ak + 2][am] = az * inv; As[ak + 3][am] = aw * inv;
    float4 bv = *reinterpret_cast<const float4*>(WtO + (size_t)(k0 + bk) * 64 + bn4);
    *reinterpret_cast<float4*>(&Bs[bk][bn4]) = bv;
    __syncthreads();
    #pragma unroll
    for (int k = 0; k < 16; ++k) {
      float4 a = *reinterpret_cast<const float4*>(&As[k][ty << 2]);
      float4 b = *reinterpret_cast<const float4*>(&Bs[k][tx << 2]);
      acc[0][0] += a.x * b.x; acc[0][1] += a.x * b.y; acc[0][2] += a.x * b.z; acc[0][3] += a.x * b.w;
      acc[1][0] += a.y * b.x; acc[1][1] += a.y * b.y; acc[1][2] += a.y * b.z; acc[1][3] += a.y * b.w;
      acc[2][0] += a.z * b.x; acc[2][1] += a.z * b.y; acc[2][2] += a.z * b.z; acc[2][3] += a.z * b.w;
      acc[3][0] += a.w * b.x; acc[3][1] += a.w * b.y; acc[3][2] += a.w * b.z; acc[3][3] += a.w * b.w;
    }
    __syncthreads();
  }
  float4 bb = *reinterpret_cast<const float4*>(ob + (tx << 2));
  #pragma unroll
  for (int i = 0; i < 4; ++i) {
    int row = bm + (ty << 2) + i;
    float o0 = acc[i][0] + bb.x, o1 = acc[i][1] + bb.y;
    float o2 = acc[i][2] + bb.z, o3 = acc[i][3] + bb.w;
    *reinterpret_cast<ushort4*>(Axpa + (size_t)row * 320 + 256 + (tx << 2)) =
        make_ushort4(f2bf(o0), f2bf(o1), f2bf(o2), f2bf(o3));
  }
}

// ---------------- bf16 MFMA GEMM for GCN layers (split-weight) ----------------

template <int K, int NT>
__global__ __launch_bounds__(256) void gemm_mfma(const ushort* __restrict__ A,
                                                 const ushort* __restrict__ Bthi,
                                                 const ushort* __restrict__ Btlo,
                                                 ushort* __restrict__ C) {
  const int t = threadIdx.x;
  const int wv = t >> 6;
  const int l = t & 63;
  const int lg = l >> 4;
  const int lc = l & 15;
  const int bm = blockIdx.y * 64;
  const int n = blockIdx.x * 64 + wv * 16 + lc;

  const ushort* ap = A + (size_t)(bm + lc) * K + lg * 8;
  const ushort* bh = Bthi + (size_t)n * K + lg * 8;
  const ushort* bl = Btlo + (size_t)n * K + lg * 8;

  f32x4 acc[4] = {{0.f,0.f,0.f,0.f},{0.f,0.f,0.f,0.f},{0.f,0.f,0.f,0.f},{0.f,0.f,0.f,0.f}};
  #pragma unroll 2
  for (int k0 = 0; k0 < K; k0 += 32) {
    bf16x8 vh = *reinterpret_cast<const bf16x8*>(bh + k0);
    bf16x8 vl = *reinterpret_cast<const bf16x8*>(bl + k0);
    #pragma unroll
    for (int mt = 0; mt < 4; ++mt) {
      bf16x8 af = *reinterpret_cast<const bf16x8*>(ap + (size_t)mt * 16 * K + k0);
      acc[mt] = __builtin_amdgcn_mfma_f32_16x16x32_bf16(af, vh, acc[mt], 0, 0, 0);
      acc[mt] = __builtin_amdgcn_mfma_f32_16x16x32_bf16(af, vl, acc[mt], 0, 0, 0);
    }
  }
  #pragma unroll
  for (int mt = 0; mt < 4; ++mt) {
    #pragma unroll
    for (int r = 0; r < 4; ++r)
      C[(size_t)(bm + mt * 16 + lg * 4 + r) * NT + n] = f2bf(acc[mt][r]);
  }
}

// ---------------- GCN aggregation (bf16 gather, fp32 accum) ----------------

template <bool RELU>
__global__ __launch_bounds__(256) void aggregate_bf(const ushort* __restrict__ hwb,
                                                    const int* __restrict__ csr,
                                                    const int* __restrict__ row_off,
                                                    const int* __restrict__ deg,
                                                    const float* __restrict__ dinv,
                                                    const float* __restrict__ bias,
                                                    ushort* __restrict__ outb) {
  __shared__ __align__(16) float part[2][256];
  const int t = threadIdx.x;
  const int rw = t >> 7;
  const int wh = (t >> 6) & 1;
  const int l = t & 63;
  const int r = blockIdx.x * 2 + rw;
  const float dr = dinv[r];
  const int off = row_off[r];
  const int cnt = deg[r] - 1;
  const int c = l << 2;

  float a0, a1, a2, a3;
  if (wh == 0) {
    ushort4 u = *reinterpret_cast<const ushort4*>(hwb + (size_t)r * 256 + c);
    a0 = dr * bf2f(u.x); a1 = dr * bf2f(u.y); a2 = dr * bf2f(u.z); a3 = dr * bf2f(u.w);
  } else {
    a0 = a1 = a2 = a3 = 0.f;
  }
  for (int e = wh; e < cnt; e += 2) {
    int s = csr[off + e];
    float wsc = dinv[s];
    ushort4 u = *reinterpret_cast<const ushort4*>(hwb + (size_t)s * 256 + c);
    a0 += wsc * bf2f(u.x); a1 += wsc * bf2f(u.y);
    a2 += wsc * bf2f(u.z); a3 += wsc * bf2f(u.w);
  }
  if (wh == 1)
    *reinterpret_cast<float4*>(&part[rw][c]) = make_float4(a0, a1, a2, a3);
  __syncthreads();
  if (wh == 0) {
    float4 p = *reinterpret_cast<const float4*>(&part[rw][c]);
    float4 bv = *reinterpret_cast<const float4*>(bias + c);
    float o0 = dr * (a0 + p.x) + bv.x;
    float o1 = dr * (a1 + p.y) + bv.y;
    float o2 = dr * (a2 + p.z) + bv.z;
    float o3 = dr * (a3 + p.w) + bv.w;
    if (RELU) {
      o0 = fmaxf(o0, 0.f); o1 = fmaxf(o1, 0.f);
      o2 = fmaxf(o2, 0.f); o3 = fmaxf(o3, 0.f);
    }
    *reinterpret_cast<ushort4*>(outb + (size_t)r * 256 + c) =
        make_ushort4(f2bf(o0), f2bf(o1), f2bf(o2), f2bf(o3));
  }
}

__global__ __launch_bounds__(256) void aggregate64_bf(const ushort* __restrict__ hwb,
                                                      const int* __restrict__ csr,
                                                      const int* __restrict__ row_off,
                                                      const int* __restrict__ deg,
                                                      const float* __restrict__ dinv,
                                                      const float* __restrict__ bias,
                                                      float* __restrict__ out) {
  const int w = threadIdx.x >> 6, l = threadIdx.x & 63;
  const int r = blockIdx.x * 4 + w;
  const float dr = dinv[r];
  const int off = row_off[r];
  const int cnt = deg[r] - 1;
  float a = dr * bf2f(hwb[(size_t)r * 64 + l]);
  for (int e = 0; e < cnt; ++e) {
    int s = csr[off + e];
    a += dinv[s] * bf2f(hwb[(size_t)s * 64 + l]);
  }
  out[(size_t)r * 64 + l] = dr * a + bias[l];
}

// ---------------- launch ----------------

extern "C" void kernel_launch(void* const* d_in, const int* in_sizes, int n_in,
                              void* d_out, int out_size, void* d_ws, size_t ws_size,
                              hipStream_t stream) {
  const float* x          = (const float*)d_in[0];
  const int*   ei         = (const int*)d_in[1];
  const float* pe_w       = (const float*)d_in[2];
  const float* pe_b       = (const float*)d_in[3];
  const float* in_proj_w  = (const float*)d_in[4];
  const float* in_proj_b  = (const float*)d_in[5];
  const float* out_proj_w = (const float*)d_in[6];
  const float* out_proj_b = (const float*)d_in[7];
  const float* w1         = (const float*)d_in[8];
  const float* b1         = (const float*)d_in[9];
  const float* w2         = (const float*)d_in[10];
  const float* b2         = (const float*)d_in[11];
  const float* w3         = (const float*)d_in[12];
  const float* b3         = (const float*)d_in[13];

  const int* esrc = ei;
  const int* edst = ei + N_EDGES;

  char* ws = (char*)d_ws;
  size_t o = 0;
  auto take = [&](size_t n) {
    char* p = ws + o;
    o += (n + 255) & ~(size_t)255;
    return p;
  };
  char*   region1 = take(18874368);                                    // 18 MB shared
  ushort* Axpa    = (ushort*)take((size_t)N_NODES * 320 * 2);          // 5 MB
  ushort* Qbf     = (ushort*)take((size_t)NHEADS * N_NODES * 32 * 2);  // 2 MB
  ushort* Kbf     = (ushort*)take((size_t)NHEADS * N_NODES * 32 * 2);  // 2 MB
  ushort* Vtb     = (ushort*)take((size_t)NHEADS * DH * N_NODES * 2);  // 1 MB
  float*  Wpp     = (float*)take((size_t)256 * 192 * 4);
  float*  bpp     = (float*)take((size_t)192 * 4);
  float*  WtO     = (float*)take((size_t)64 * 64 * 4);
  ushort* Bt1hi   = (ushort*)take((size_t)HID * 320 * 2);
  ushort* Bt1lo   = (ushort*)take((size_t)HID * 320 * 2);
  ushort* Bt2hi   = (ushort*)take((size_t)HID * HID * 2);
  ushort* Bt2lo   = (ushort*)take((size_t)HID * HID * 2);
  ushort* Bt3hi   = (ushort*)take((size_t)OUT_DIM * HID * 2);
  ushort* Bt3lo   = (ushort*)take((size_t)OUT_DIM * HID * 2);
  float*  dinv    = (float*)take((size_t)N_NODES * 4);
  int*    deg     = (int*)take((size_t)N_NODES * 4);
  int*    cursor  = (int*)take((size_t)N_NODES * 4);
  int*    row_off = (int*)take((size_t)N_NODES * 4);
  int*    csr     = (int*)take((size_t)N_EDGES * 4);

  // region1 phase A (attention): Opart 16 MB + Wpart 1 MB.
  float* Opart = (float*)region1;
  float* Wpart = (float*)(region1 + 16777216);
  // region1 phase B (GCN trunk; starts after gemm_pa finished reading Opart):
  ushort* hwbf = (ushort*)region1;                 // [8192][256]  4 MB
  ushort* h1bf = hwbf + (size_t)N_NODES * 256;     // [8192][256]  4 MB
  ushort* h2bf = h1bf + (size_t)N_NODES * 256;     // [8192][256]  4 MB
  ushort* hw64 = h2bf + (size_t)N_NODES * 256;     // [8192][64]   1 MB

  // graph preprocessing
  init_graph<<<N_NODES / 256, 256, 0, stream>>>(deg, cursor);
  count_deg<<<N_EDGES / 256, 256, 0, stream>>>(edst, deg);
  scan_rows<<<1, 256, 0, stream>>>(deg, row_off, dinv);
  fill_csr<<<N_EDGES / 256, 256, 0, stream>>>(esrc, edst, row_off, cursor, csr);

  // fused prep (weights + x->bf16)
  prep<<<2897, 256, 0, stream>>>(x, pe_w, pe_b, in_proj_w, in_proj_b, out_proj_w,
                                 w1, w2, w3, Axpa, Wpp, bpp, WtO,
                                 Bt1hi, Bt1lo, Bt2hi, Bt2lo, Bt3hi, Bt3lo);

  // attention path
  gemm_qkv<<<dim3(3, 128), 256, 0, stream>>>(x, Wpp, bpp, Qbf, Kbf, Vtb);
  attn_mfma5<<<dim3(128, 4, KSPLIT), 256, 0, stream>>>(Qbf, Kbf, Vtb, Opart, Wpart);
  gemm_pa<<<dim3(1, 128), 256, 0, stream>>>(Opart, Wpart, WtO, out_proj_b, Axpa);

  // GCN trunk (bf16 storage, fp32 accumulation, split-weight MFMA)
  gemm_mfma<320, 256><<<dim3(4, 128), 256, 0, stream>>>(Axpa, Bt1hi, Bt1lo, hwbf);
  aggregate_bf<true><<<N_NODES / 2, 256, 0, stream>>>(hwbf, csr, row_off, deg, dinv, b1, h1bf);
  gemm_mfma<256, 256><<<dim3(4, 128), 256, 0, stream>>>(h1bf, Bt2hi, Bt2lo, hwbf);
  aggregate_bf<true><<<N_NODES / 2, 256, 0, stream>>>(hwbf, csr, row_off, deg, dinv, b2, h2bf);
  gemm_mfma<256, 64><<<dim3(1, 128), 256, 0, stream>>>(h2bf, Bt3hi, Bt3lo, hw64);
  aggregate64_bf<<<N_NODES / 4, 256, 0, stream>>>(hw64, csr, row_off, deg, dinv, b3, (float*)d_out);
}

// Round 13
// 271.234 us; speedup vs baseline: 1.0292x; 1.0292x over previous
//
#include <hip/hip_runtime.h>
#include <hip/hip_bf16.h>

#define N_NODES 8192
#define N_EDGES 262144
#define IN_DIM 256
#define HID 256
#define OUT_DIM 64
#define PATH_DIM 64
#define NHEADS 4
#define DH 16
#define KSPLIT 8
#define SPLIT_KEYS (N_NODES / KSPLIT)   // 1024
#define NITER (SPLIT_KEYS / 64)         // 16

typedef __attribute__((ext_vector_type(8))) short bf16x8;
typedef __attribute__((ext_vector_type(4))) short bf16x4;
typedef __attribute__((ext_vector_type(4))) float f32x4;

__device__ __forceinline__ ushort f2bf(float f) {
  union { float f; unsigned int u; } c;
  c.f = f;
  unsigned int u = c.u;
  u += 0x7fffu + ((u >> 16) & 1u);
  return (ushort)(u >> 16);
}

__device__ __forceinline__ float bf2f(ushort u) {
  union { float f; unsigned int u; } c;
  c.u = ((unsigned int)u) << 16;
  return c.f;
}

__device__ __forceinline__ float fast_exp2(float x) {
  float r;
  asm("v_exp_f32 %0, %1" : "=v"(r) : "v"(x));
  return r;
}

__device__ __forceinline__ unsigned pack_bf16(float a, float b) {
  union { __hip_bfloat162 h; unsigned u; } c;
  c.h = __float22bfloat162_rn(make_float2(a, b));
  return c.u;
}

// PV matrix op: 16x16x16 bf16 (K=16).
#if __has_builtin(__builtin_amdgcn_mfma_f32_16x16x16bf16_1k)
__device__ __forceinline__ f32x4 mfma16(bf16x4 a, bf16x4 b, f32x4 c) {
  return __builtin_amdgcn_mfma_f32_16x16x16bf16_1k(a, b, c, 0, 0, 0);
}
#else
__device__ __forceinline__ f32x4 mfma16(bf16x4 a, bf16x4 b, f32x4 c) {
  f32x4 d;
  asm volatile("v_mfma_f32_16x16x16_bf16 %0, %1, %2, %3\n\ts_nop 7\n\ts_nop 3"
               : "=v"(d) : "v"(a), "v"(b), "v"(c));
  return d;
}
#endif

// ---------------- graph setup ----------------

__global__ __launch_bounds__(256) void count_deg(const int* __restrict__ dst,
                                                 int* __restrict__ deg) {
  int e = blockIdx.x * 256 + threadIdx.x;
  if (e < N_EDGES) atomicAdd(&deg[dst[e]], 1);
}

__global__ __launch_bounds__(256) void scan_rows(const int* __restrict__ deg,
                                                 int* __restrict__ row_off,
                                                 float* __restrict__ dinv) {
  __shared__ int part[256];
  int t = threadIdx.x;
  int base = t * 32;
  int local[32];
  int s = 0;
  #pragma unroll
  for (int i = 0; i < 32; ++i) {
    int c = deg[base + i] - 1;
    local[i] = s;
    s += c;
  }
  part[t] = s;
  __syncthreads();
  for (int d = 1; d < 256; d <<= 1) {
    int v = (t >= d) ? part[t - d] : 0;
    __syncthreads();
    part[t] += v;
    __syncthreads();
  }
  int prev = (t == 0) ? 0 : part[t - 1];
  #pragma unroll
  for (int i = 0; i < 32; ++i) {
    row_off[base + i] = prev + local[i];
    dinv[base + i] = rsqrtf((float)deg[base + i]);
  }
}

__global__ __launch_bounds__(256) void fill_csr(const int* __restrict__ src,
                                                const int* __restrict__ dst,
                                                const int* __restrict__ row_off,
                                                int* __restrict__ cursor,
                                                int* __restrict__ csr) {
  int e = blockIdx.x * 256 + threadIdx.x;
  if (e < N_EDGES) {
    int d = dst[e];
    int p = atomicAdd(&cursor[d], 1);
    csr[row_off[d] + p] = src[e];
  }
}

// ---------------- fused prep ----------------
// block ranges:
//  [0,2048)     convert x -> Axpa[:,0:256] bf16
//  [2048,2240)  W'' = pe_w @ in_proj_w^T  (cols<64 scaled by SC)  [256][192]
//  [2240]       b'' = pe_b @ in_proj_w^T + in_proj_b (cols<64 * SC)
//  [2241,2305)  W1b'' = out_proj_w^T @ w1[256:] fold -> Bt1 rows k=256..319 (hi/lo)
//  [2305]       crow[m] = sum_c ob[c]*w1[256+c][m]
//  [2306,2338)  init deg=1, cursor=0
//  [2338,2594)  w1[0:256] split -> Bt1[n][k<256]
//  [2594,2850)  w2 split
//  [2850,2914)  w3 split

__global__ __launch_bounds__(256) void prep(const float* __restrict__ x,
                                            const float* __restrict__ pe_w,
                                            const float* __restrict__ pe_b,
                                            const float* __restrict__ in_proj_w,
                                            const float* __restrict__ in_proj_b,
                                            const float* __restrict__ out_proj_w,
                                            const float* __restrict__ ob,
                                            const float* __restrict__ w1,
                                            const float* __restrict__ w2,
                                            const float* __restrict__ w3,
                                            ushort* __restrict__ Axpa,
                                            float* __restrict__ Wpp,
                                            float* __restrict__ bpp,
                                            float* __restrict__ crow,
                                            int* __restrict__ deg,
                                            int* __restrict__ cursor,
                                            ushort* __restrict__ Bt1hi, ushort* __restrict__ Bt1lo,
                                            ushort* __restrict__ Bt2hi, ushort* __restrict__ Bt2lo,
                                            ushort* __restrict__ Bt3hi, ushort* __restrict__ Bt3lo) {
  const float SC = 0.36067376022224085f;  // 0.25 * log2(e)
  const int b = blockIdx.x;
  const int t = threadIdx.x;
  if (b < 2048) {
    int e = b * 256 + t;
    int n = e >> 6, qi = (e & 63) << 2;
    float4 v = *reinterpret_cast<const float4*>(x + (size_t)n * 256 + qi);
    *reinterpret_cast<ushort4*>(Axpa + (size_t)n * 320 + qi) =
        make_ushort4(f2bf(v.x), f2bf(v.y), f2bf(v.z), f2bf(v.w));
  } else if (b < 2240) {
    int e = (b - 2048) * 256 + t;
    int k = e / 192, c = e % 192;
    float s = 0.f;
    for (int j = 0; j < 64; ++j) s += pe_w[k * 64 + j] * in_proj_w[c * 64 + j];
    if (c < 64) s *= SC;
    Wpp[k * 192 + c] = s;
  } else if (b == 2240) {
    if (t < 192) {
      float s = 0.f;
      for (int j = 0; j < 64; ++j) s += pe_b[j] * in_proj_w[t * 64 + j];
      s += in_proj_b[t];
      if (t < 64) s *= SC;
      bpp[t] = s;
    }
  } else if (b < 2305) {
    // W1b''[d][m] = sum_c out_proj_w[c][d] * w1[(256+c)*256 + m]
    int e = (b - 2241) * 256 + t;   // 0..16383
    int d = e >> 8, m = e & 255;
    float s = 0.f;
    for (int c = 0; c < 64; ++c)
      s += out_proj_w[c * 64 + d] * w1[(size_t)(256 + c) * 256 + m];
    ushort hi = f2bf(s);
    Bt1hi[(size_t)m * 320 + 256 + d] = hi;
    Bt1lo[(size_t)m * 320 + 256 + d] = f2bf(s - bf2f(hi));
  } else if (b == 2305) {
    // crow[m] = sum_c ob[c] * w1[(256+c)*256 + m]
    float s = 0.f;
    for (int c = 0; c < 64; ++c) s += ob[c] * w1[(size_t)(256 + c) * 256 + t];
    crow[t] = s;
  } else if (b < 2338) {
    int i = (b - 2306) * 256 + t;
    deg[i] = 1;       // self loop
    cursor[i] = 0;
  } else if (b < 2594) {
    int e = (b - 2338) * 256 + t;   // w1 rows 0..255
    int k = e >> 8, n = e & 255;
    float v = w1[e];
    ushort hi = f2bf(v);
    Bt1hi[(size_t)n * 320 + k] = hi;
    Bt1lo[(size_t)n * 320 + k] = f2bf(v - bf2f(hi));
  } else if (b < 2850) {
    int e = (b - 2594) * 256 + t;
    int k = e >> 8, n = e & 255;
    float v = w2[e];
    ushort hi = f2bf(v);
    Bt2hi[(size_t)n * 256 + k] = hi;
    Bt2lo[(size_t)n * 256 + k] = f2bf(v - bf2f(hi));
  } else {
    int e = (b - 2850) * 256 + t;
    int k = e >> 6, n = e & 63;
    float v = w3[e];
    ushort hi = f2bf(v);
    Bt3hi[(size_t)n * 256 + k] = hi;
    Bt3lo[(size_t)n * 256 + k] = f2bf(v - bf2f(hi));
  }
}

// ---------------- qkv GEMM: x[8192x256] @ W''[256x192] + b'' -> Qbf/Kbf/Vtb bf16 ----------------

__global__ __launch_bounds__(256) void gemm_qkv(const float* __restrict__ x,
                                                const float* __restrict__ Wpp,
                                                const float* __restrict__ bpp,
                                                ushort* __restrict__ Qbf,
                                                ushort* __restrict__ Kbf,
                                                ushort* __restrict__ Vtb) {
  __shared__ __align__(16) float As[16][64];
  __shared__ __align__(16) float Bs[16][68];
  const int bm = blockIdx.y * 64;
  const int bx = blockIdx.x;
  const int bn = bx * 64;
  const int t = threadIdx.x;
  const int tx = t & 15, ty = t >> 4;
  const int am = t >> 2, ak = (t & 3) << 2;
  const int bk = t >> 4, bn4 = (t & 15) << 2;
  float acc[4][4] = {};
  for (int k0 = 0; k0 < 256; k0 += 16) {
    float4 av = *reinterpret_cast<const float4*>(x + (size_t)(bm + am) * 256 + k0 + ak);
    As[ak + 0][am] = av.x; As[ak + 1][am] = av.y;
    As[ak + 2][am] = av.z; As[ak + 3][am] = av.w;
    float4 bv = *reinterpret_cast<const float4*>(Wpp + (size_t)(k0 + bk) * 192 + bn + bn4);
    *reinterpret_cast<float4*>(&Bs[bk][bn4]) = bv;
    __syncthreads();
    #pragma unroll
    for (int k = 0; k < 16; ++k) {
      float4 a = *reinterpret_cast<const float4*>(&As[k][ty << 2]);
      float4 b = *reinterpret_cast<const float4*>(&Bs[k][tx << 2]);
      acc[0][0] += a.x * b.x; acc[0][1] += a.x * b.y; acc[0][2] += a.x * b.z; acc[0][3] += a.x * b.w;
      acc[1][0] += a.y * b.x; acc[1][1] += a.y * b.y; acc[1][2] += a.y * b.z; acc[1][3] += a.y * b.w;
      acc[2][0] += a.z * b.x; acc[2][1] += a.z * b.y; acc[2][2] += a.z * b.z; acc[2][3] += a.z * b.w;
      acc[3][0] += a.w * b.x; acc[3][1] += a.w * b.y; acc[3][2] += a.w * b.z; acc[3][3] += a.w * b.w;
    }
    __syncthreads();
  }
  const int cl = tx << 2;
  const int h = cl >> 4, d = cl & 15;
  float4 bb = *reinterpret_cast<const float4*>(bpp + bn + cl);
  const ushort4 zz = make_ushort4(0, 0, 0, 0);
  #pragma unroll
  for (int i = 0; i < 4; ++i) {
    int row = bm + (ty << 2) + i;
    float o0 = acc[i][0] + bb.x, o1 = acc[i][1] + bb.y;
    float o2 = acc[i][2] + bb.z, o3 = acc[i][3] + bb.w;
    ushort4 u = make_ushort4(f2bf(o0), f2bf(o1), f2bf(o2), f2bf(o3));
    if (bx == 0) {
      *reinterpret_cast<ushort4*>(Qbf + ((size_t)h * 8192 + row) * 32 + d) = u;
      *reinterpret_cast<ushort4*>(Qbf + ((size_t)h * 8192 + row) * 32 + d + 16) = zz;
    } else if (bx == 1) {
      *reinterpret_cast<ushort4*>(Kbf + ((size_t)h * 8192 + row) * 32 + d) = u;
      *reinterpret_cast<ushort4*>(Kbf + ((size_t)h * 8192 + row) * 32 + d + 16) = zz;
    } else {
      Vtb[((size_t)h * 16 + d + 0) * 8192 + row] = u.x;
      Vtb[((size_t)h * 16 + d + 1) * 8192 + row] = u.y;
      Vtb[((size_t)h * 16 + d + 2) * 8192 + row] = u.z;
      Vtb[((size_t)h * 16 + d + 3) * 8192 + row] = u.w;
    }
  }
}

// ---------------- MFMA flash attention v5.1 (round-12 proven form) ----------------

__global__ __launch_bounds__(256) void attn_mfma5(const ushort* __restrict__ Qbf,
                                                  const ushort* __restrict__ Kbf,
                                                  const ushort* __restrict__ Vtb,
                                                  float* __restrict__ Opart,
                                                  float* __restrict__ Wpart) {
  const int h  = blockIdx.y;
  const int qb = blockIdx.x;
  const int kz = blockIdx.z;
  const int t  = threadIdx.x;
  const int wv = t >> 6;
  const int l  = t & 63;
  const int lg = l >> 4;
  const int lc = l & 15;

  __shared__ float red_o[3][64][17];
  __shared__ float red_w[3][64];

  bf16x8 qf[4];
  {
    const ushort* qbase = Qbf + ((size_t)h * 8192 + qb * 64) * 32;
    #pragma unroll
    for (int qt = 0; qt < 4; ++qt)
      qf[qt] = *reinterpret_cast<const bf16x8*>(qbase + (qt * 16 + lc) * 32 + lg * 8);
  }

  const ushort* kptr =
      Kbf + ((size_t)h * 8192 + kz * SPLIT_KEYS + wv * 16 + lc) * 32 + lg * 8;
  const ushort* vptr =
      Vtb + ((size_t)h * 16 + lc) * 8192 + kz * SPLIT_KEYS + wv * 16 + lg * 4;

  f32x4 oacc[4] = {{0.f, 0.f, 0.f, 0.f}, {0.f, 0.f, 0.f, 0.f},
                   {0.f, 0.f, 0.f, 0.f}, {0.f, 0.f, 0.f, 0.f}};
  float wsum[4] = {0.f, 0.f, 0.f, 0.f};

  bf16x8 kf = *reinterpret_cast<const bf16x8*>(kptr);
  bf16x4 vf = *reinterpret_cast<const bf16x4*>(vptr);

  for (int c = 0; c < NITER; ++c) {
    bf16x8 kf_n;
    bf16x4 vf_n;
    if (c + 1 < NITER) {
      kf_n = *reinterpret_cast<const bf16x8*>(kptr + (size_t)(c + 1) * 64 * 32);
      vf_n = *reinterpret_cast<const bf16x4*>(vptr + (size_t)(c + 1) * 64);
    }

    f32x4 s[4];
    #pragma unroll
    for (int qt = 0; qt < 4; ++qt) {
      f32x4 z = {0.f, 0.f, 0.f, 0.f};
      s[qt] = __builtin_amdgcn_mfma_f32_16x16x32_bf16(kf, qf[qt], z, 0, 0, 0);
    }

    #pragma unroll
    for (int qt = 0; qt < 4; ++qt) {
      float e0 = fast_exp2(s[qt][0]);
      float e1 = fast_exp2(s[qt][1]);
      float e2 = fast_exp2(s[qt][2]);
      float e3 = fast_exp2(s[qt][3]);
      wsum[qt] += (e0 + e1) + (e2 + e3);
      union { uint2 u; bf16x4 v; } pu;
      pu.u.x = pack_bf16(e0, e1);
      pu.u.y = pack_bf16(e2, e3);
      oacc[qt] = mfma16(pu.v, vf, oacc[qt]);
    }

    kf = kf_n;
    vf = vf_n;
  }

  #pragma unroll
  for (int qt = 0; qt < 4; ++qt) {
    float v = wsum[qt];
    v += __shfl_xor(v, 16);
    v += __shfl_xor(v, 32);
    wsum[qt] = v;   // strip total for q = qt*16 + lc
  }

  if (wv > 0) {
    #pragma unroll
    for (int qt = 0; qt < 4; ++qt) {
      #pragma unroll
      for (int r = 0; r < 4; ++r)
        red_o[wv - 1][qt * 16 + lg * 4 + r][lc] = oacc[qt][r];
      if (lg == 0) red_w[wv - 1][qt * 16 + lc] = wsum[qt];
    }
  }
  __syncthreads();

  if (wv == 0) {
    const size_t obase = ((size_t)(kz * NHEADS + h) * N_NODES + qb * 64);
    #pragma unroll
    for (int qt = 0; qt < 4; ++qt) {
      #pragma unroll
      for (int r = 0; r < 4; ++r) {
        const int q = qt * 16 + lg * 4 + r;
        float o = oacc[qt][r] + red_o[0][q][lc] + red_o[1][q][lc] + red_o[2][q][lc];
        Opart[(obase + q) * 16 + lc] = o;
      }
      if (lg == 0) {
        const int q = qt * 16 + lc;
        Wpart[obase + q] = wsum[qt] + red_w[0][q] + red_w[1][q] + red_w[2][q];
      }
    }
  }
}

// combine splits, normalize, write bf16 A into Axpa[:,256:320]
__global__ __launch_bounds__(256) void attn_combine_bf(const float* __restrict__ Opart,
                                                       const float* __restrict__ Wpart,
                                                       ushort* __restrict__ Axpa) {
  int i = blockIdx.x * 256 + threadIdx.x;  // 0 .. 4*8192*4-1
  int dq = i & 3;
  int hn = i >> 2;
  int h = hn >> 13;
  int n = hn & 8191;
  float4 acc = make_float4(0.f, 0.f, 0.f, 0.f);
  float ws = 0.f;
  #pragma unroll
  for (int s = 0; s < KSPLIT; ++s) {
    const size_t row = ((size_t)(s * NHEADS + h) * N_NODES + n);
    float4 v = *reinterpret_cast<const float4*>(Opart + row * 16 + dq * 4);
    acc.x += v.x; acc.y += v.y; acc.z += v.z; acc.w += v.w;
    ws += Wpart[row];
  }
  float inv = 1.f / ws;
  *reinterpret_cast<ushort4*>(Axpa + (size_t)n * 320 + 256 + h * 16 + dq * 4) =
      make_ushort4(f2bf(acc.x * inv), f2bf(acc.y * inv),
                   f2bf(acc.z * inv), f2bf(acc.w * inv));
}

// ---------------- bf16 MFMA GEMM for GCN layers (split-weight, optional crow) ----------------

template <int K, int NT, bool CROW>
__global__ __launch_bounds__(256) void gemm_mfma(const ushort* __restrict__ A,
                                                 const ushort* __restrict__ Bthi,
                                                 const ushort* __restrict__ Btlo,
                                                 const float* __restrict__ crow,
                                                 ushort* __restrict__ C) {
  const int t = threadIdx.x;
  const int wv = t >> 6;
  const int l = t & 63;
  const int lg = l >> 4;
  const int lc = l & 15;
  const int bm = blockIdx.y * 64;
  const int n = blockIdx.x * 64 + wv * 16 + lc;

  const ushort* ap = A + (size_t)(bm + lc) * K + lg * 8;
  const ushort* bh = Bthi + (size_t)n * K + lg * 8;
  const ushort* bl = Btlo + (size_t)n * K + lg * 8;

  f32x4 acc[4] = {{0.f,0.f,0.f,0.f},{0.f,0.f,0.f,0.f},{0.f,0.f,0.f,0.f},{0.f,0.f,0.f,0.f}};
  #pragma unroll 2
  for (int k0 = 0; k0 < K; k0 += 32) {
    bf16x8 vh = *reinterpret_cast<const bf16x8*>(bh + k0);
    bf16x8 vl = *reinterpret_cast<const bf16x8*>(bl + k0);
    #pragma unroll
    for (int mt = 0; mt < 4; ++mt) {
      bf16x8 af = *reinterpret_cast<const bf16x8*>(ap + (size_t)mt * 16 * K + k0);
      acc[mt] = __builtin_amdgcn_mfma_f32_16x16x32_bf16(af, vh, acc[mt], 0, 0, 0);
      acc[mt] = __builtin_amdgcn_mfma_f32_16x16x32_bf16(af, vl, acc[mt], 0, 0, 0);
    }
  }
  const float cr = CROW ? crow[n] : 0.f;
  #pragma unroll
  for (int mt = 0; mt < 4; ++mt) {
    #pragma unroll
    for (int r = 0; r < 4; ++r)
      C[(size_t)(bm + mt * 16 + lg * 4 + r) * NT + n] = f2bf(acc[mt][r] + cr);
  }
}

// ---------------- GCN aggregation (bf16 gather, fp32 accum, 4-way edge split) ----------------
// 1 row per block, 4 waves; wave wv handles edges e ≡ wv (mod 4); LDS combine.

template <bool RELU>
__global__ __launch_bounds__(256) void aggregate4_bf(const ushort* __restrict__ hwb,
                                                     const int* __restrict__ csr,
                                                     const int* __restrict__ row_off,
                                                     const int* __restrict__ deg,
                                                     const float* __restrict__ dinv,
                                                     const float* __restrict__ bias,
                                                     ushort* __restrict__ outb) {
  __shared__ __align__(16) float part[3][256];
  const int t = threadIdx.x;
  const int wv = t >> 6;
  const int l = t & 63;
  const int r = blockIdx.x;
  const float dr = dinv[r];
  const int off = row_off[r];
  const int cnt = deg[r] - 1;
  const int c = l << 2;

  float a0, a1, a2, a3;
  if (wv == 0) {
    ushort4 u = *reinterpret_cast<const ushort4*>(hwb + (size_t)r * 256 + c);
    a0 = dr * bf2f(u.x); a1 = dr * bf2f(u.y); a2 = dr * bf2f(u.z); a3 = dr * bf2f(u.w);
  } else {
    a0 = a1 = a2 = a3 = 0.f;
  }
  for (int e = wv; e < cnt; e += 4) {
    int s = csr[off + e];
    float wsc = dinv[s];
    ushort4 u = *reinterpret_cast<const ushort4*>(hwb + (size_t)s * 256 + c);
    a0 += wsc * bf2f(u.x); a1 += wsc * bf2f(u.y);
    a2 += wsc * bf2f(u.z); a3 += wsc * bf2f(u.w);
  }
  if (wv > 0)
    *reinterpret_cast<float4*>(&part[wv - 1][c]) = make_float4(a0, a1, a2, a3);
  __syncthreads();
  if (wv == 0) {
    float4 p0 = *reinterpret_cast<const float4*>(&part[0][c]);
    float4 p1 = *reinterpret_cast<const float4*>(&part[1][c]);
    float4 p2 = *reinterpret_cast<const float4*>(&part[2][c]);
    float4 bv = *reinterpret_cast<const float4*>(bias + c);
    float o0 = dr * (a0 + p0.x + p1.x + p2.x) + bv.x;
    float o1 = dr * (a1 + p0.y + p1.y + p2.y) + bv.y;
    float o2 = dr * (a2 + p0.z + p1.z + p2.z) + bv.z;
    float o3 = dr * (a3 + p0.w + p1.w + p2.w) + bv.w;
    if (RELU) {
      o0 = fmaxf(o0, 0.f); o1 = fmaxf(o1, 0.f);
      o2 = fmaxf(o2, 0.f); o3 = fmaxf(o3, 0.f);
    }
    *reinterpret_cast<ushort4*>(outb + (size_t)r * 256 + c) =
        make_ushort4(f2bf(o0), f2bf(o1), f2bf(o2), f2bf(o3));
  }
}

__global__ __launch_bounds__(256) void aggregate64_bf(const ushort* __restrict__ hwb,
                                                      const int* __restrict__ csr,
                                                      const int* __restrict__ row_off,
                                                      const int* __restrict__ deg,
                                                      const float* __restrict__ dinv,
                                                      const float* __restrict__ bias,
                                                      float* __restrict__ out) {
  const int w = threadIdx.x >> 6, l = threadIdx.x & 63;
  const int r = blockIdx.x * 4 + w;
  const float dr = dinv[r];
  const int off = row_off[r];
  const int cnt = deg[r] - 1;
  float a = dr * bf2f(hwb[(size_t)r * 64 + l]);
  for (int e = 0; e < cnt; ++e) {
    int s = csr[off + e];
    a += dinv[s] * bf2f(hwb[(size_t)s * 64 + l]);
  }
  out[(size_t)r * 64 + l] = dr * a + bias[l];
}

// ---------------- launch ----------------

extern "C" void kernel_launch(void* const* d_in, const int* in_sizes, int n_in,
                              void* d_out, int out_size, void* d_ws, size_t ws_size,
                              hipStream_t stream) {
  const float* x          = (const float*)d_in[0];
  const int*   ei         = (const int*)d_in[1];
  const float* pe_w       = (const float*)d_in[2];
  const float* pe_b       = (const float*)d_in[3];
  const float* in_proj_w  = (const float*)d_in[4];
  const float* in_proj_b  = (const float*)d_in[5];
  const float* out_proj_w = (const float*)d_in[6];
  const float* out_proj_b = (const float*)d_in[7];
  const float* w1         = (const float*)d_in[8];
  const float* b1         = (const float*)d_in[9];
  const float* w2         = (const float*)d_in[10];
  const float* b2         = (const float*)d_in[11];
  const float* w3         = (const float*)d_in[12];
  const float* b3         = (const float*)d_in[13];

  const int* esrc = ei;
  const int* edst = ei + N_EDGES;

  char* ws = (char*)d_ws;
  size_t o = 0;
  auto take = [&](size_t n) {
    char* p = ws + o;
    o += (n + 255) & ~(size_t)255;
    return p;
  };
  char*   region1 = take(18874368);                                    // 18 MB shared
  ushort* Axpa    = (ushort*)take((size_t)N_NODES * 320 * 2);          // 5 MB
  ushort* Qbf     = (ushort*)take((size_t)NHEADS * N_NODES * 32 * 2);  // 2 MB
  ushort* Kbf     = (ushort*)take((size_t)NHEADS * N_NODES * 32 * 2);  // 2 MB
  ushort* Vtb     = (ushort*)take((size_t)NHEADS * DH * N_NODES * 2);  // 1 MB
  float*  Wpp     = (float*)take((size_t)256 * 192 * 4);
  float*  bpp     = (float*)take((size_t)192 * 4);
  float*  crow    = (float*)take((size_t)256 * 4);
  ushort* Bt1hi   = (ushort*)take((size_t)HID * 320 * 2);
  ushort* Bt1lo   = (ushort*)take((size_t)HID * 320 * 2);
  ushort* Bt2hi   = (ushort*)take((size_t)HID * HID * 2);
  ushort* Bt2lo   = (ushort*)take((size_t)HID * HID * 2);
  ushort* Bt3hi   = (ushort*)take((size_t)OUT_DIM * HID * 2);
  ushort* Bt3lo   = (ushort*)take((size_t)OUT_DIM * HID * 2);
  float*  dinv    = (float*)take((size_t)N_NODES * 4);
  int*    deg     = (int*)take((size_t)N_NODES * 4);
  int*    cursor  = (int*)take((size_t)N_NODES * 4);
  int*    row_off = (int*)take((size_t)N_NODES * 4);
  int*    csr     = (int*)take((size_t)N_EDGES * 4);

  // region1 phase A (attention): Opart 16 MB + Wpart 1 MB.
  float* Opart = (float*)region1;
  float* Wpart = (float*)(region1 + 16777216);
  // region1 phase B (GCN trunk; starts after attn_combine_bf finished reading):
  ushort* hwbf = (ushort*)region1;                 // [8192][256]  4 MB
  ushort* h1bf = hwbf + (size_t)N_NODES * 256;     // [8192][256]  4 MB
  ushort* h2bf = h1bf + (size_t)N_NODES * 256;     // [8192][256]  4 MB
  ushort* hw64 = h2bf + (size_t)N_NODES * 256;     // [8192][64]   1 MB

  // fused prep (weights, x->bf16, graph init)
  prep<<<2914, 256, 0, stream>>>(x, pe_w, pe_b, in_proj_w, in_proj_b, out_proj_w,
                                 out_proj_b, w1, w2, w3, Axpa, Wpp, bpp, crow,
                                 deg, cursor,
                                 Bt1hi, Bt1lo, Bt2hi, Bt2lo, Bt3hi, Bt3lo);

  // graph preprocessing
  count_deg<<<N_EDGES / 256, 256, 0, stream>>>(edst, deg);
  scan_rows<<<1, 256, 0, stream>>>(deg, row_off, dinv);
  fill_csr<<<N_EDGES / 256, 256, 0, stream>>>(esrc, edst, row_off, cursor, csr);

  // attention path
  gemm_qkv<<<dim3(3, 128), 256, 0, stream>>>(x, Wpp, bpp, Qbf, Kbf, Vtb);
  attn_mfma5<<<dim3(128, 4, KSPLIT), 256, 0, stream>>>(Qbf, Kbf, Vtb, Opart, Wpart);
  attn_combine_bf<<<(NHEADS * N_NODES * 4) / 256, 256, 0, stream>>>(Opart, Wpart, Axpa);

  // GCN trunk (bf16 storage, fp32 accumulation, split-weight MFMA; out_proj folded into layer 1)
  gemm_mfma<320, 256, true><<<dim3(4, 128), 256, 0, stream>>>(Axpa, Bt1hi, Bt1lo, crow, hwbf);
  aggregate4_bf<true><<<N_NODES, 256, 0, stream>>>(hwbf, csr, row_off, deg, dinv, b1, h1bf);
  gemm_mfma<256, 256, false><<<dim3(4, 128), 256, 0, stream>>>(h1bf, Bt2hi, Bt2lo, nullptr, hwbf);
  aggregate4_bf<true><<<N_NODES, 256, 0, stream>>>(hwbf, csr, row_off, deg, dinv, b2, h2bf);
  gemm_mfma<256, 64, false><<<dim3(1, 128), 256, 0, stream>>>(h2bf, Bt3hi, Bt3lo, nullptr, hw64);
  aggregate64_bf<<<N_NODES / 4, 256, 0, stream>>>(hw64, csr, row_off, deg, dinv, b3, (float*)d_out);
}